// Round 2
// baseline (68.597 us; speedup 1.0000x reference)
//
#include <hip/hip_runtime.h>
#include <math.h>

// PeriodicGeometryAdapter: per (b,n,m) pair, min over 27 periodic images of
// the Gram-metric squared distance; outputs concatenated flat:
//   [0]         pair_delta_min (B,N,N,3)
//   [3*S]       pair_dist      (B,N,N)      S = B*N*N
//   [4*S]       pair_dist2     (B,N,N)
//   [5*S]       pair_dist_norm (B,N,N)
//   [6*S]       pair_mask      (B,N,N)  (bool -> 1.0f/0.0f)
//   [7*S]       lattice_y1     (B,6)
//   [7*S+6B]    gram           (B,3,3)
//   [7*S+6B+9B] cell_scale     (B,1)
//
// Kernel 1 (prep): per-batch transcendentals (exp/tanh), gram, cell_scale ->
//   d_ws (8 floats per batch) + the three small per-batch outputs.
// Kernel 2 (main): one thread per (n,m) pair; reads gram via wave-uniform
//   loads; 27-image argmin with FP order identical to the JAX einsum.

__global__ __launch_bounds__(64) void pga_prep(
    const float* __restrict__ lattice,  // (B,6)
    float* __restrict__ out,
    float* __restrict__ gws,            // (B,8): G00,G01,G02,G11,G12,G22,cs,pad
    int B, size_t S)
{
    const int b = threadIdx.x;
    if (b >= B) return;
    const float l0 = lattice[b*6+0], l1 = lattice[b*6+1], l2 = lattice[b*6+2];
    const float l3 = lattice[b*6+3], l4 = lattice[b*6+4], l5 = lattice[b*6+5];
    const float la = expf(l0), lb = expf(l1), lc = expf(l2);
    const float ca = tanhf(l3), cb = tanhf(l4), cg = tanhf(l5);
    const float G00 = la*la;
    const float G01 = la*lb*cg;
    const float G02 = la*lc*cb;
    const float G11 = lb*lb;
    const float G12 = lb*lc*ca;
    const float G22 = lc*lc;
    const float cs  = fmaxf((la + lb + lc) * (1.0f/3.0f), 1e-8f);

    gws[b*8+0] = G00; gws[b*8+1] = G01; gws[b*8+2] = G02;
    gws[b*8+3] = G11; gws[b*8+4] = G12; gws[b*8+5] = G22;
    gws[b*8+6] = cs;

    float* lat_o  = out + 7*S;                 // (B,6)
    float* gram_o = lat_o + (size_t)B*6;       // (B,9)
    float* cs_o   = gram_o + (size_t)B*9;      // (B,)
    lat_o[b*6+0] = l0; lat_o[b*6+1] = l1; lat_o[b*6+2] = l2;
    lat_o[b*6+3] = l3; lat_o[b*6+4] = l4; lat_o[b*6+5] = l5;
    gram_o[b*9+0] = G00; gram_o[b*9+1] = G01; gram_o[b*9+2] = G02;
    gram_o[b*9+3] = G01; gram_o[b*9+4] = G11; gram_o[b*9+5] = G12;
    gram_o[b*9+6] = G02; gram_o[b*9+7] = G12; gram_o[b*9+8] = G22;
    cs_o[b] = cs;
}

__global__ __launch_bounds__(256) void pga_main(
    const float* __restrict__ coords,           // (B,N,3)
    const unsigned char* __restrict__ pad_mask, // (B,N) bool
    const float* __restrict__ gws,              // (B,8)
    float* __restrict__ out,
    int B, int N)
{
    const int b = blockIdx.y;
    const int n = blockIdx.x;
    const int m = threadIdx.x;      // blockDim.x == N

    // wave-uniform per-batch constants (b uniform -> scalar loads)
    const float G00 = gws[b*8+0], G01 = gws[b*8+1], G02 = gws[b*8+2];
    const float G11 = gws[b*8+3], G12 = gws[b*8+4], G22 = gws[b*8+5];
    const float cs  = gws[b*8+6];

    const float xn = coords[((size_t)b*N + n)*3 + 0];
    const float yn = coords[((size_t)b*N + n)*3 + 1];
    const float zn = coords[((size_t)b*N + n)*3 + 2];
    const float xm = coords[((size_t)b*N + m)*3 + 0];
    const float ym = coords[((size_t)b*N + m)*3 + 1];
    const float zm = coords[((size_t)b*N + m)*3 + 2];
    const float dx = xn - xm, dy = yn - ym, dz = zn - zm;

    // axis values (identical FP to dx + (float)o, o in {-1,0,1})
    const float ax0 = dx - 1.0f, ax1 = dx, ax2 = dx + 1.0f;
    const float ay0 = dy - 1.0f, ay1 = dy, ay2 = dy + 1.0f;
    const float az0 = dz - 1.0f, az1 = dz, az2 = dz + 1.0f;

    // per-axis row products (27 mults, shared across images; association of the
    // einsum sums is preserved exactly: t = (px+py)+pz, d2 = (t0*x+t1*y)+t2*z)
    const float p0x0 = ax0*G00, p0x1 = ax1*G00, p0x2 = ax2*G00;
    const float p1x0 = ax0*G01, p1x1 = ax1*G01, p1x2 = ax2*G01;
    const float p2x0 = ax0*G02, p2x1 = ax1*G02, p2x2 = ax2*G02;
    const float p0y0 = ay0*G01, p0y1 = ay1*G01, p0y2 = ay2*G01;
    const float p1y0 = ay0*G11, p1y1 = ay1*G11, p1y2 = ay2*G11;
    const float p2y0 = ay0*G12, p2y1 = ay1*G12, p2y2 = ay2*G12;
    const float p0z0 = az0*G02, p0z1 = az1*G02, p0z2 = az2*G02;
    const float p1z0 = az0*G12, p1z1 = az1*G12, p1z2 = az2*G12;
    const float p2z0 = az0*G22, p2z1 = az1*G22, p2z2 = az2*G22;

    float best_d2 = INFINITY;
    int bestCode = 0;

#define IMG(i, j, k)                                                          \
    {                                                                         \
        const float t0 = (p0x##i + p0y##j) + p0z##k;                          \
        const float t1 = (p1x##i + p1y##j) + p1z##k;                          \
        const float t2 = (p2x##i + p2y##j) + p2z##k;                          \
        const float d2 = (t0*ax##i + t1*ay##j) + t2*az##k;                    \
        if (d2 < best_d2) { best_d2 = d2; bestCode = i*9 + j*3 + k; }         \
    }

    IMG(0,0,0) IMG(0,0,1) IMG(0,0,2)
    IMG(0,1,0) IMG(0,1,1) IMG(0,1,2)
    IMG(0,2,0) IMG(0,2,1) IMG(0,2,2)
    IMG(1,0,0) IMG(1,0,1) IMG(1,0,2)
    IMG(1,1,0) IMG(1,1,1) IMG(1,1,2)
    IMG(1,2,0) IMG(1,2,1) IMG(1,2,2)
    IMG(2,0,0) IMG(2,0,1) IMG(2,0,2)
    IMG(2,1,0) IMG(2,1,1) IMG(2,1,2)
    IMG(2,2,0) IMG(2,2,1) IMG(2,2,2)
#undef IMG

    // reconstruct winning delta arithmetically (no runtime register indexing)
    const int bi = bestCode / 9;
    const int bj = (bestCode - bi*9) / 3;
    const int bk = bestCode - bi*9 - bj*3;
    float bx = dx + (float)(bi - 1);
    float by = dy + (float)(bj - 1);
    float bz = dz + (float)(bk - 1);

    const bool valid_n = (pad_mask[(size_t)b*N + n] == 0);
    const bool valid_m = (pad_mask[(size_t)b*N + m] == 0);
    const bool pm = valid_n && valid_m;

    float d2c  = fmaxf(best_d2, 0.0f);
    float dist = sqrtf(d2c);
    float dnrm = dist / cs;
    if (!pm) { bx = by = bz = 0.f; dist = 0.f; d2c = 0.f; dnrm = 0.f; }

    const size_t S = (size_t)B * N * N;
    const size_t p = ((size_t)b * N + n) * N + m;

    out[3*p + 0] = bx;
    out[3*p + 1] = by;
    out[3*p + 2] = bz;
    out[3*S + p] = dist;
    out[4*S + p] = d2c;
    out[5*S + p] = dnrm;
    out[6*S + p] = pm ? 1.0f : 0.0f;
}

extern "C" void kernel_launch(void* const* d_in, const int* in_sizes, int n_in,
                              void* d_out, int out_size, void* d_ws, size_t ws_size,
                              hipStream_t stream) {
    const float*         coords   = (const float*)d_in[0];
    const unsigned char* pad_mask = (const unsigned char*)d_in[1];
    const float*         lattice  = (const float*)d_in[2];
    float* out = (float*)d_out;
    float* gws = (float*)d_ws;

    const int B = in_sizes[2] / 6;          // lattice (B,6)
    const int N = in_sizes[1] / B;          // pad_mask (B,N)
    const size_t S = (size_t)B * N * N;

    pga_prep<<<dim3(1), dim3(64), 0, stream>>>(lattice, out, gws, B, S);
    pga_main<<<dim3(N, B), dim3(N), 0, stream>>>(coords, pad_mask, gws, out, B, N);
}